// Round 5
// baseline (1467.072 us; speedup 1.0000x reference)
//
#include <hip/hip_runtime.h>

typedef unsigned short u16;
typedef unsigned int u32;
typedef unsigned long long u64;
typedef __attribute__((ext_vector_type(8))) short bf16x8;
typedef __attribute__((ext_vector_type(4))) float f32x4;

#define N_NODES 20000
#define N_EDGES 160000
#define DDIM    1000
#define KP      1024            // padded K / row stride (elements)
#define SP      41200000        // node-buffer spacing (bytes)
#define WCAT_L  6291456         // per-layer wcat elems = 3*1024*2048

__device__ __forceinline__ float b2f(u16 u) {
    union { u32 i; float f; } v; v.i = ((u32)u) << 16; return v.f;
}
__device__ __forceinline__ u16 f2b(float f) {
    union { float f; u32 i; } v; v.f = f;
    u32 r = v.i + 0x7FFFu + ((v.i >> 16) & 1u);
    return (u16)(r >> 16);
}
__device__ __forceinline__ u32 pack2(float a, float b) {
    return (u32)f2b(a) | ((u32)f2b(b) << 16);
}
__device__ __forceinline__ f32x4 mfma16(bf16x8 a, bf16x8 b, f32x4 c) {
    return __builtin_amdgcn_mfma_f32_16x16x32_bf16(a, b, c, 0, 0, 0);
}
// fast transcendentals: v_exp_f32 / v_rcp_f32 (approx err << bf16 rounding)
__device__ __forceinline__ float fexp_(float x) {
    return __builtin_amdgcn_exp2f(x * 1.4426950408889634f);
}
__device__ __forceinline__ float fsigmoid_(float x) {
    return __builtin_amdgcn_rcpf(1.0f + fexp_(-x));   // x->-inf: rcp(inf)=0 ok
}
__device__ __forceinline__ float ftanh_(float x) {
    float ax = fabsf(x);
    float e = fexp_(-2.0f * ax);                       // e in (0,1], no overflow
    float t = (1.0f - e) * __builtin_amdgcn_rcpf(1.0f + e);
    return x >= 0.0f ? t : -t;
}

// async global->LDS DMA, 16 B per lane; lds dest = wave-uniform base + lane*16
__device__ __forceinline__ void gl2lds16(const u16* g, u16* l) {
    __builtin_amdgcn_global_load_lds(
        (const __attribute__((address_space(1))) u32*)g,
        (__attribute__((address_space(3))) u32*)l, 16, 0, 0);
}

// ---------------------------------------------------------------------------
// fp32 [rows][1000] -> bf16 [rows][1024], zero-padded cols. One block per row.
// ---------------------------------------------------------------------------
__global__ __launch_bounds__(256) void cvt_rows(const float* __restrict__ in,
                                                u16* __restrict__ out) {
    int r = blockIdx.x, c = threadIdx.x * 4;
    u32 o[2] = {0, 0};
    if (c < DDIM) {
        float4 v = *(const float4*)(in + (size_t)r * DDIM + c);
        o[0] = pack2(v.x, v.y); o[1] = pack2(v.z, v.w);
    }
    *(uint2*)(out + (size_t)r * KP + c) = *(const uint2*)o;
}

// ---------------------------------------------------------------------------
// Merged weight conversions (one dispatch, grid 15000):
//   b in [0,3000):      wih row b        -> wihb [3072][1024] (stride KP)
//   b in [3000,6000):   W row (b-3000)   -> Wb3 [3][1024][1024]
//   b in [6000,15000):  whh row, layer l -> wcat_l phase-2 half (+1024)
// All k-pads (c>=1000) written zero.
// ---------------------------------------------------------------------------
__global__ __launch_bounds__(256) void cvt_weights(const float* __restrict__ wih,
                                                   const float* __restrict__ W,
                                                   const float* __restrict__ whh,
                                                   u16* __restrict__ wihb,
                                                   u16* __restrict__ Wb3,
                                                   u16* __restrict__ wcat) {
    int b = blockIdx.x, c = threadIdx.x * 4;
    const float* src;
    u16* dst;
    if (b < 3000) {
        src = wih + (size_t)b * DDIM;
        dst = wihb + (size_t)b * KP;
    } else if (b < 6000) {
        int r = b - 3000;                    // 0..2999 = l*1000 + row
        int l = r / 1000, row = r - l * 1000;
        src = W + (size_t)r * DDIM;
        dst = Wb3 + (size_t)l * 1048576 + (size_t)row * KP;
    } else {
        int r = b - 6000;                    // 0..8999: l = r/3000, gr = r%3000
        int l = r / 3000, gr = r - l * 3000;
        int g = gr / 1000, n2 = gr - g * 1000;
        src = whh + (size_t)gr * DDIM;
        dst = wcat + (size_t)l * WCAT_L + ((size_t)g * 1024 + n2) * 2048 + 1024;
    }
    u32 o[2] = {0, 0};
    if (c < DDIM) {
        float4 v = *(const float4*)(src + c);
        o[0] = pack2(v.x, v.y); o[1] = pack2(v.z, v.w);
    }
    *(uint2*)(dst + c) = *(const uint2*)o;
}

// ---------------------------------------------------------------------------
// CSR build (edge list constant): count -> scan -> fill
// ---------------------------------------------------------------------------
__global__ __launch_bounds__(256) void count_edges(const int* __restrict__ ei,
                                                   int* __restrict__ cnt) {
    int e = blockIdx.x * 256 + threadIdx.x;
    if (e < N_EDGES) atomicAdd(&cnt[ei[N_EDGES + e]], 1);
}

__global__ __launch_bounds__(1024) void scan_offsets(const int* __restrict__ cnt,
                                                     int* __restrict__ ofs) {
    __shared__ int s[1024];
    const int CH = 20;
    int t = threadIdx.x;
    int base = t * CH;
    int loc[CH];
    int sum = 0;
    for (int j = 0; j < CH; j++) {
        int i = base + j;
        loc[j] = sum;
        sum += (i < N_NODES) ? cnt[i] : 0;
    }
    s[t] = sum;
    __syncthreads();
    for (int d = 1; d < 1024; d <<= 1) {
        int v = (t >= d) ? s[t - d] : 0;
        __syncthreads();
        s[t] += v;
        __syncthreads();
    }
    int excl = s[t] - sum;
    for (int j = 0; j < CH; j++) {
        int i = base + j;
        if (i < N_NODES) ofs[i] = excl + loc[j];
    }
    if (t == 0) ofs[N_NODES] = N_EDGES;
}

__global__ __launch_bounds__(256) void fill_buckets(const int* __restrict__ ei,
                                                    const int* __restrict__ ofs,
                                                    int* __restrict__ cur,
                                                    int* __restrict__ bkt) {
    int e = blockIdx.x * 256 + threadIdx.x;
    if (e >= N_EDGES) return;
    int d = ei[N_EDGES + e];
    int pos = atomicAdd(&cur[d], 1);
    bkt[ofs[d] + pos] = e;
}

// ---------------------------------------------------------------------------
// t[node] = sum_{e: dst=node} h[src(e)] * ew[e] — TWO nodes per block
// (half = tid>>7), uint4 gathers (125 lanes x 16 B = one 2 KB row / edge).
// Sum order per element identical to the 1-node version (bitwise-same agg).
// Threads 125..127 of each half zero k-pad cols 1000..1023.
// ---------------------------------------------------------------------------
__global__ __launch_bounds__(256) void node_agg(const int* __restrict__ ei,
                                                const float* __restrict__ ew,
                                                const int* __restrict__ ofs,
                                                const int* __restrict__ bkt,
                                                const u16* __restrict__ hsrc,
                                                u16* __restrict__ agg) {
    __shared__ int   s_src[2][32];
    __shared__ float s_w[2][32];
    __shared__ int   s_it[2];
    int tid = threadIdx.x;
    int half = tid >> 7, t = tid & 127;
    int node = blockIdx.x * 2 + half;        // grid 10000 -> nodes 0..19999
    int beg = ofs[node], end = ofs[node + 1];
    if (t == 0) s_it[half] = (end - beg + 31) >> 5;
    __syncthreads();
    int iters = max(s_it[0], s_it[1]);
    float acc[8] = {};
    for (int it = 0; it < iters; it++) {
        int cb = beg + it * 32;
        int n = min(32, end - cb);           // may be <= 0 for the short half
        if (t < n) {
            int e = bkt[cb + t];
            s_src[half][t] = ei[e];
            s_w[half][t]   = ew[e];
        }
        __syncthreads();
        if (t < 125) {
            for (int j = 0; j < n; j++) {
                int src = s_src[half][j];
                float w = s_w[half][j];
                uint4 v = *(const uint4*)(hsrc + (size_t)src * KP + t * 8);
                const u16* p = (const u16*)&v;
#pragma unroll
                for (int k = 0; k < 8; k++) acc[k] += b2f(p[k]) * w;
            }
        }
        __syncthreads();
    }
    if (t < 125) {
        u32 o[4] = {pack2(acc[0], acc[1]), pack2(acc[2], acc[3]),
                    pack2(acc[4], acc[5]), pack2(acc[6], acc[7])};
        *(uint4*)(agg + (size_t)node * KP + t * 8) = *(const uint4*)o;
    } else if (t < 128) {                    // zero pad cols 1000..1023
        uint4 z = {0, 0, 0, 0};
        *(uint4*)(agg + (size_t)node * KP + 1000 + (t - 125) * 8) = z;
    }
}

// ---------------------------------------------------------------------------
// Wc precompute: Wc_l[g, din] = sum_dout wihb[g][dout] * Wb3_l[din][dout]
// -> written into phase-1 half of wcat_l (slab = g/1000, row = g%1000).
// 128x128 tile, BK=64, XOR-swizzled staging. grid (192, 3).
// ---------------------------------------------------------------------------
__global__ __launch_bounds__(256) void gemm_wc(const u16* __restrict__ A,
                                               const u16* __restrict__ Bt3,
                                               u16* __restrict__ wcat) {
    __shared__ u16 S[16384];             // Sa [128][64] @0, Sb @8192 (u16 idx)
    int tid = threadIdx.x;
    int lane = tid & 63, wave = tid >> 6;
    int wr = wave >> 1, wc = wave & 1;
    int bid = blockIdx.x;
    int l = blockIdx.y;
    int m0 = (bid >> 3) * 128, n0 = (bid & 7) * 128;
    const u16* Bt = Bt3 + (size_t)l * 1048576;

    int aoff[4], boff[4];
#pragma unroll
    for (int i = 0; i < 4; i++) {
        int c = tid + 256 * i;
        int row = c >> 3, sl = c & 7;
        int kc = sl ^ (row & 7);
        aoff[i] = (m0 + row) * KP + kc * 8;
        boff[i] = (n0 + row) * KP + kc * 8;
    }
    f32x4 acc[4][4] = {};
    int fr = lane & 15, q = lane >> 4, sw = fr & 7;

    for (int k0 = 0; k0 < KP; k0 += 64) {
#pragma unroll
        for (int i = 0; i < 4; i++) {
            gl2lds16(A + aoff[i] + k0, &S[tid * 8 + 2048 * i]);
            gl2lds16(Bt + boff[i] + k0, &S[8192 + tid * 8 + 2048 * i]);
        }
        __syncthreads();
#pragma unroll
        for (int ks = 0; ks < 2; ks++) {
            int kx = ((ks * 4 + q) ^ sw) * 8;
            bf16x8 af[4], bf[4];
#pragma unroll
            for (int i = 0; i < 4; i++)
                af[i] = *(const bf16x8*)&S[(wr * 64 + i * 16 + fr) * 64 + kx];
#pragma unroll
            for (int j = 0; j < 4; j++)
                bf[j] = *(const bf16x8*)&S[8192 + (wc * 64 + j * 16 + fr) * 64 + kx];
#pragma unroll
            for (int i = 0; i < 4; i++)
#pragma unroll
                for (int j = 0; j < 4; j++)
                    acc[i][j] = mfma16(af[i], bf[j], acc[i][j]);
        }
        __syncthreads();
    }

    u16* wl = wcat + (size_t)l * WCAT_L;
    int cc = lane & 15, r4 = q * 4;
#pragma unroll
    for (int i = 0; i < 4; i++)
#pragma unroll
        for (int j = 0; j < 4; j++) {
            int gn = n0 + wc * 64 + j * 16 + cc;     // din column
            if (gn >= DDIM) continue;
#pragma unroll
            for (int r = 0; r < 4; r++) {
                int gm = m0 + wr * 64 + i * 16 + r4 + r;   // gate row 0..3071
                if (gm >= 3000) continue;
                int slab = (gm >= 2000) ? 2 : (gm >= 1000 ? 1 : 0);
                int row = gm - slab * 1000;
                wl[(size_t)slab * 2097152 + (size_t)row * 2048 + gn] =
                    f2b(acc[i][j][r]);
            }
        }
}

// ---------------------------------------------------------------------------
// Fused GRU, A-direct-to-register with REGISTER double-buffer (R4 fix):
//   R4 failed on LATENCY: af(t) issued end of t-1, awaited ~200 cyc later ->
//   ~2000 cyc exposed L2 latency per tile (dur 392, MfmaUtil 27.6, both pipes
//   idle). Fix: ping-pong af registers (afA/afB, +16 VGPR, paid for by
//   cutting W-frag liveness 16->8) and issue af(t+1) at the TOP of tile t —
//   a full tile (~2000+ cyc) before first use.
//   Per-tile (one barrier, counted vmcnt, ledger verified for all t):
//     enter: [W(t)3, af(t)8]
//     vmcnt(8)  -> W(t) retired (issued a tile ago, ~0 stall)
//     s_barrier -> all waves' W(t) visible; buf^1 reads of t-1 all done
//     STAGE_W(t+1)[3]; LOAD_AF(t+1 -> afNxt)[8]   (outstanding 19)
//     vmcnt(11) -> af(t) retired (issued a tile ago, ~0 stall)
//     sched_barrier(0); 48 MFMA from afCur + 12 W ds_reads (per (g,j) pair)
//   LDS holds only W (2 x 24 KB): 96 ds_read_b128/CU/tile = 1152 cyc <
//   MFMA 1862 cyc -> MFMA-bound once latency is hidden.
//   Numerics bitwise-identical (same data, same per-acc MFMA order).
// ---------------------------------------------------------------------------
__global__ __launch_bounds__(512, 2) void gru_fused(const u16* __restrict__ agg,
                                                    const u16* __restrict__ h,
                                                    const u16* __restrict__ wcat,
                                                    const float* __restrict__ bih,
                                                    const float* __restrict__ bhh,
                                                    u16* __restrict__ hout) {
    extern __shared__ u16 S[];            // W double buffer: 2 x 12288 u16 (48 KB)
    int tid = threadIdx.x;
    int lane = tid & 63, wave = tid >> 6;
    int wr = wave >> 1, wc = wave & 1;    // wave tile: rows wr*64.., cols wc*32..

    int bid = blockIdx.x;                 // grid 1264 = 8 xcd x (79 panels x 2 hi)
    int xcd = bid & 7;
    int s = bid >> 3;                     // 0..157
    int panel = s >> 1, hi = s & 1;
    int m0 = panel * 256;                 // rows >= 20000: finite garbage, masked
    int n0 = (xcd * 2 + hi) * 64;

    // W staging map (XOR swizzle): slot c (row=c>>3, sl=c&7), kc = sl^(row&7)
    int wrow = tid >> 3;                  // 0..63
    int woff = (n0 + wrow) * 2048 + ((tid & 7) ^ (wrow & 7)) * 8;

    f32x4 aR[4][2] = {}, aZ[4][2] = {}, aN[4][2] = {}, aH[4][2] = {};
    int fr = lane & 15, q = lane >> 4, sw = fr & 7;
    int kx0 = (q ^ sw) * 8, kx1 = ((4 + q) ^ sw) * 8;
    int wcol[2];
#pragma unroll
    for (int j = 0; j < 2; j++) wcol[j] = (wc * 32 + j * 16 + fr) * 64;
    // af global BYTE offsets (per-lane): row(fr)*KP + q*8 elems, x2 bytes
    u32 aroB[4];
#pragma unroll
    for (int i = 0; i < 4; i++)
        aroB[i] = (u32)(((m0 + wr * 64 + i * 16 + fr) * KP + q * 8) * 2);

    bf16x8 afA[4][2], afB[4][2];          // ping-pong A fragments

#define STAGE_W(ts) do {                                                      \
        int kw_ = (ts) * 64;                                                  \
        _Pragma("unroll")                                                     \
        for (int g_ = 0; g_ < 3; g_++)                                        \
            gl2lds16(wcat + (size_t)g_ * 2097152 + woff + kw_,                \
                     &S[((ts) & 1) * 12288 + g_ * 4096 + tid * 8]);           \
    } while (0)

// asm loads, 64-bit vaddr form (ISA §7): deterministic issue order vs gl2lds
// (vmcnt ledger depends on it). offset:0 -> k=q*8; offset:64 -> +32 elems.
#define LOAD_AF(ts, DST) do {                                                 \
        const u16* ap_ = ((ts) < 16) ? (agg + (ts) * 64)                      \
                                     : (h + ((ts) * 64 - 1024));              \
        _Pragma("unroll")                                                     \
        for (int i_ = 0; i_ < 4; i_++) {                                      \
            u64 ab_ = (u64)ap_ + aroB[i_];                                    \
            asm volatile("global_load_dwordx4 %0, %1, off offset:0"           \
                : "=v"(DST[i_][0]) : "v"(ab_) : "memory");                    \
            asm volatile("global_load_dwordx4 %0, %1, off offset:64"          \
                : "=v"(DST[i_][1]) : "v"(ab_) : "memory");                    \
        }                                                                     \
    } while (0)

// one gate: 4 ds_read_b128 (8 VGPR live) + 16 MFMA; per-acc order = ks0,ks1
#define GATE(g_, ACC, AF) do {                                                \
        _Pragma("unroll")                                                     \
        for (int j_ = 0; j_ < 2; j_++) {                                      \
            bf16x8 w0_ = *(const bf16x8*)&S[Wb + (g_) * 4096 + wcol[j_] + kx0];\
            bf16x8 w1_ = *(const bf16x8*)&S[Wb + (g_) * 4096 + wcol[j_] + kx1];\
            _Pragma("unroll")                                                 \
            for (int i_ = 0; i_ < 4; i_++) {                                  \
                ACC[i_][j_] = mfma16(AF[i_][0], w0_, ACC[i_][j_]);            \
                ACC[i_][j_] = mfma16(AF[i_][1], w1_, ACC[i_][j_]);            \
            }                                                                 \
        }                                                                     \
    } while (0)

#define TILE(t, WBC, AFC, AFN) do {                                           \
        asm volatile("s_waitcnt vmcnt(8)" ::: "memory");                      \
        __builtin_amdgcn_s_barrier();                                         \
        if ((t) <= 30) {                                                      \
            STAGE_W((t) + 1);                                                 \
            LOAD_AF((t) + 1, AFN);                                            \
            asm volatile("s_waitcnt vmcnt(11)" ::: "memory");                 \
        } else {                                                              \
            asm volatile("s_waitcnt vmcnt(0)" ::: "memory");                  \
        }                                                                     \
        __builtin_amdgcn_sched_barrier(0);                                    \
        {                                                                     \
            const int Wb = (WBC);                                             \
            GATE(0, aR, AFC);                                                 \
            GATE(1, aZ, AFC);                                                 \
            if ((t) < 16) GATE(2, aN, AFC); else GATE(2, aH, AFC);            \
        }                                                                     \
    } while (0)

    // prologue: W(0)[3] then af(0)[8] -> enter loop with [W(0)3, afA(0)8]
    STAGE_W(0);
    LOAD_AF(0, afA);

#pragma unroll 1
    for (int tt = 0; tt < 32; tt += 2) {
        TILE(tt,     0,     afA, afB);
        TILE(tt + 1, 12288, afB, afA);
    }
#undef STAGE_W
#undef LOAD_AF
#undef GATE
#undef TILE

    // epilogue: gate math + h blend (same numerics as previous kernel)
    int cc = lane & 15, r4 = q * 4;
#pragma unroll
    for (int j = 0; j < 2; j++) {
        int gn = n0 + wc * 32 + j * 16 + cc;
        if (gn >= DDIM) continue;
        float br  = bih[gn] + bhh[gn];
        float bz  = bih[1000 + gn] + bhh[1000 + gn];
        float bni = bih[2000 + gn];
        float bnh = bhh[2000 + gn];
#pragma unroll
        for (int i = 0; i < 4; i++)
#pragma unroll
            for (int r = 0; r < 4; r++) {
                int gm = m0 + wr * 64 + i * 16 + r4 + r;
                if (gm >= N_NODES) continue;
                float rg = fsigmoid_(aR[i][j][r] + br);
                float zg = fsigmoid_(aZ[i][j][r] + bz);
                float ng = ftanh_(aN[i][j][r] + bni + rg * (aH[i][j][r] + bnh));
                size_t idx = (size_t)gm * KP + gn;
                float hp = b2f(h[idx]);
                hout[idx] = f2b((1.0f - zg) * ng + zg * hp);
            }
    }
}

// ---------------------------------------------------------------------------
// out[row] (fp32) = relu(h[row]) . fc_w + fc_b — one wave per row, uint4 loads
// ---------------------------------------------------------------------------
__global__ __launch_bounds__(256) void fc_out(const u16* __restrict__ h,
                                              const float* __restrict__ fw,
                                              const float* __restrict__ fb,
                                              float* __restrict__ out) {
    int row = blockIdx.x * 4 + (threadIdx.x >> 6);
    int lane = threadIdx.x & 63;
    if (row >= N_NODES) return;
    float s = 0.0f;
#pragma unroll
    for (int i = 0; i < 2; i++) {
        int c = lane + 64 * i;               // chunk of 8 elems
        if (c < 125) {
            uint4 v = *(const uint4*)(h + (size_t)row * KP + c * 8);
            const u16* pv = (const u16*)&v;
            float4 w0 = *(const float4*)(fw + c * 8);
            float4 w1 = *(const float4*)(fw + c * 8 + 4);
            const float* wp = (const float*)&w0;
            float hv;
#pragma unroll
            for (int k = 0; k < 4; k++) {
                hv = b2f(pv[k]);
                s += (hv > 0.0f ? hv : 0.0f) * wp[k];
            }
            wp = (const float*)&w1;
#pragma unroll
            for (int k = 0; k < 4; k++) {
                hv = b2f(pv[4 + k]);
                s += (hv > 0.0f ? hv : 0.0f) * wp[k];
            }
        }
    }
    for (int off = 32; off > 0; off >>= 1) s += __shfl_down(s, off, 64);
    if (lane == 0) out[row] = s + fb[0];
}

// ---------------------------------------------------------------------------
extern "C" void kernel_launch(void* const* d_in, const int* in_sizes, int n_in,
                              void* d_out, int out_size, void* d_ws, size_t ws_size,
                              hipStream_t stream) {
    const float* x   = (const float*)d_in[0];
    const int*   ei  = (const int*)d_in[1];
    const float* ew  = (const float*)d_in[2];
    const float* W   = (const float*)d_in[3];
    const float* wih = (const float*)d_in[4];
    const float* whh = (const float*)d_in[5];
    const float* bih = (const float*)d_in[6];
    const float* bhh = (const float*)d_in[7];
    const float* fw  = (const float*)d_in[8];
    const float* fb  = (const float*)d_in[9];
    float* out = (float*)d_out;

    // allow 48 KB dynamic LDS for gru_fused (idempotent, not a stream op)
    hipFuncSetAttribute((const void*)gru_fused,
                        hipFuncAttributeMaxDynamicSharedMemorySize, 49152);

    // workspace (~163 MB)
    char* ws = (char*)d_ws;
    u16* xb   = (u16*)(ws);                    // [20096][1024] bf16
    u16* bufA = (u16*)(ws + (size_t)SP);       // h rotation / setup scratch
    u16* bufB = (u16*)(ws + (size_t)2 * SP);   // t (aggregate)
    u16* wcat = (u16*)(ws + 123600000);        // 37.75 MB [3][3][1024][2048]
    int* cnt  = (int*)(ws + 161400000);        // 80 KB   (cur adjacent)
    int* cur  = (int*)(ws + 161480000);        // 80 KB
    int* ofs  = (int*)(ws + 161560000);        // 80 KB + 4
    int* bkt  = (int*)(ws + 161640192);        // 640 KB

    // setup scratch inside bufA (free until layer-0 gru output)
    u16* wihb = bufA;                          // [3072][1024] (rows>=3000 junk ok)
    u16* Wb3  = bufA + 3145728;                // [3][1024][1024] (rows>=1000 junk ok)

    // one-time conversions + Wc precompute + CSR build.
    // No wcat memset: k-pad cols of valid outputs always multiply a ZERO A-pad
    // (cvt_rows / node_agg write zero pads; 0xAA poison is finite bf16), and
    // garbage weight ROWS feed only gn>=1000 outputs which epilogues discard.
    cvt_rows<<<N_NODES, 256, 0, stream>>>(x, xb);
    cvt_weights<<<15000, 256, 0, stream>>>(wih, W, whh, wihb, Wb3, wcat);
    gemm_wc<<<dim3(192, 3), 256, 0, stream>>>(wihb, Wb3, wcat);
    hipMemsetAsync(cnt, 0, 160000, stream);    // cnt + cur (contiguous)
    count_edges<<<625, 256, 0, stream>>>(ei, cnt);
    scan_offsets<<<1, 1024, 0, stream>>>(cnt, ofs);
    fill_buckets<<<625, 256, 0, stream>>>(ei, ofs, cur, bkt);

    // layer 0: t = S*x -> bufB; h1 = GRU(t, xb, wcat0) -> bufA
    node_agg<<<10000, 256, 0, stream>>>(ei, ew, ofs, bkt, xb, bufB);
    gru_fused<<<1264, 512, 49152, stream>>>(bufB, xb, wcat, bih, bhh, bufA);

    // layer 1: t = S*h1 -> bufB; h2 = GRU(t, bufA, wcat1) -> xb
    node_agg<<<10000, 256, 0, stream>>>(ei, ew, ofs, bkt, bufA, bufB);
    gru_fused<<<1264, 512, 49152, stream>>>(bufB, bufA, wcat + WCAT_L, bih, bhh, xb);

    // layer 2: t = S*h2 -> bufB; h3 = GRU(t, xb, wcat2) -> bufA
    node_agg<<<10000, 256, 0, stream>>>(ei, ew, ofs, bkt, xb, bufB);
    gru_fused<<<1264, 512, 49152, stream>>>(bufB, xb, wcat + 2 * WCAT_L, bih, bhh, bufA);

    // out = relu(h3) @ fc_w^T + fc_b
    fc_out<<<5000, 256, 0, stream>>>(bufA, fw, fb, out);
}

// Round 6
// 1124.488 us; speedup vs baseline: 1.3047x; 1.3047x over previous
//
#include <hip/hip_runtime.h>

typedef unsigned short u16;
typedef unsigned int u32;
typedef unsigned long long u64;
typedef __attribute__((ext_vector_type(8))) short bf16x8;
typedef __attribute__((ext_vector_type(4))) float f32x4;

#define N_NODES 20000
#define N_EDGES 160000
#define DDIM    1000
#define KP      1024            // padded K / row stride (elements)
#define SP      41200000        // node-buffer spacing (bytes)
#define WCAT_L  6291456         // per-layer wcat elems = 3*1024*2048

__device__ __forceinline__ float b2f(u16 u) {
    union { u32 i; float f; } v; v.i = ((u32)u) << 16; return v.f;
}
__device__ __forceinline__ u16 f2b(float f) {
    union { float f; u32 i; } v; v.f = f;
    u32 r = v.i + 0x7FFFu + ((v.i >> 16) & 1u);
    return (u16)(r >> 16);
}
__device__ __forceinline__ u32 pack2(float a, float b) {
    return (u32)f2b(a) | ((u32)f2b(b) << 16);
}
__device__ __forceinline__ f32x4 mfma16(bf16x8 a, bf16x8 b, f32x4 c) {
    return __builtin_amdgcn_mfma_f32_16x16x32_bf16(a, b, c, 0, 0, 0);
}
// fast transcendentals: v_exp_f32 / v_rcp_f32 (approx err << bf16 rounding)
__device__ __forceinline__ float fexp_(float x) {
    return __builtin_amdgcn_exp2f(x * 1.4426950408889634f);
}
__device__ __forceinline__ float fsigmoid_(float x) {
    return __builtin_amdgcn_rcpf(1.0f + fexp_(-x));   // x->-inf: rcp(inf)=0 ok
}
__device__ __forceinline__ float ftanh_(float x) {
    float ax = fabsf(x);
    float e = fexp_(-2.0f * ax);                       // e in (0,1], no overflow
    float t = (1.0f - e) * __builtin_amdgcn_rcpf(1.0f + e);
    return x >= 0.0f ? t : -t;
}

// async global->LDS DMA, 16 B per lane; lds dest = wave-uniform base + lane*16
__device__ __forceinline__ void gl2lds16(const u16* g, u16* l) {
    __builtin_amdgcn_global_load_lds(
        (const __attribute__((address_space(1))) u32*)g,
        (__attribute__((address_space(3))) u32*)l, 16, 0, 0);
}

// ---------------------------------------------------------------------------
// fp32 [rows][1000] -> bf16 [rows][1024], zero-padded cols. One block per row.
// ---------------------------------------------------------------------------
__global__ __launch_bounds__(256) void cvt_rows(const float* __restrict__ in,
                                                u16* __restrict__ out) {
    int r = blockIdx.x, c = threadIdx.x * 4;
    u32 o[2] = {0, 0};
    if (c < DDIM) {
        float4 v = *(const float4*)(in + (size_t)r * DDIM + c);
        o[0] = pack2(v.x, v.y); o[1] = pack2(v.z, v.w);
    }
    *(uint2*)(out + (size_t)r * KP + c) = *(const uint2*)o;
}

// ---------------------------------------------------------------------------
// Merged weight conversions (one dispatch, grid 15000):
//   b in [0,3000):      wih row b        -> wihb [3072][1024] (stride KP)
//   b in [3000,6000):   W row (b-3000)   -> Wb3 [3][1024][1024]
//   b in [6000,15000):  whh row, layer l -> wcat_l phase-2 half (+1024)
// All k-pads (c>=1000) written zero.
// ---------------------------------------------------------------------------
__global__ __launch_bounds__(256) void cvt_weights(const float* __restrict__ wih,
                                                   const float* __restrict__ W,
                                                   const float* __restrict__ whh,
                                                   u16* __restrict__ wihb,
                                                   u16* __restrict__ Wb3,
                                                   u16* __restrict__ wcat) {
    int b = blockIdx.x, c = threadIdx.x * 4;
    const float* src;
    u16* dst;
    if (b < 3000) {
        src = wih + (size_t)b * DDIM;
        dst = wihb + (size_t)b * KP;
    } else if (b < 6000) {
        int r = b - 3000;                    // 0..2999 = l*1000 + row
        int l = r / 1000, row = r - l * 1000;
        src = W + (size_t)r * DDIM;
        dst = Wb3 + (size_t)l * 1048576 + (size_t)row * KP;
    } else {
        int r = b - 6000;                    // 0..8999: l = r/3000, gr = r%3000
        int l = r / 3000, gr = r - l * 3000;
        int g = gr / 1000, n2 = gr - g * 1000;
        src = whh + (size_t)gr * DDIM;
        dst = wcat + (size_t)l * WCAT_L + ((size_t)g * 1024 + n2) * 2048 + 1024;
    }
    u32 o[2] = {0, 0};
    if (c < DDIM) {
        float4 v = *(const float4*)(src + c);
        o[0] = pack2(v.x, v.y); o[1] = pack2(v.z, v.w);
    }
    *(uint2*)(dst + c) = *(const uint2*)o;
}

// ---------------------------------------------------------------------------
// CSR build (edge list constant): count -> scan -> fill
// ---------------------------------------------------------------------------
__global__ __launch_bounds__(256) void count_edges(const int* __restrict__ ei,
                                                   int* __restrict__ cnt) {
    int e = blockIdx.x * 256 + threadIdx.x;
    if (e < N_EDGES) atomicAdd(&cnt[ei[N_EDGES + e]], 1);
}

__global__ __launch_bounds__(1024) void scan_offsets(const int* __restrict__ cnt,
                                                     int* __restrict__ ofs) {
    __shared__ int s[1024];
    const int CH = 20;
    int t = threadIdx.x;
    int base = t * CH;
    int loc[CH];
    int sum = 0;
    for (int j = 0; j < CH; j++) {
        int i = base + j;
        loc[j] = sum;
        sum += (i < N_NODES) ? cnt[i] : 0;
    }
    s[t] = sum;
    __syncthreads();
    for (int d = 1; d < 1024; d <<= 1) {
        int v = (t >= d) ? s[t - d] : 0;
        __syncthreads();
        s[t] += v;
        __syncthreads();
    }
    int excl = s[t] - sum;
    for (int j = 0; j < CH; j++) {
        int i = base + j;
        if (i < N_NODES) ofs[i] = excl + loc[j];
    }
    if (t == 0) ofs[N_NODES] = N_EDGES;
}

__global__ __launch_bounds__(256) void fill_buckets(const int* __restrict__ ei,
                                                    const int* __restrict__ ofs,
                                                    int* __restrict__ cur,
                                                    int* __restrict__ bkt) {
    int e = blockIdx.x * 256 + threadIdx.x;
    if (e >= N_EDGES) return;
    int d = ei[N_EDGES + e];
    int pos = atomicAdd(&cur[d], 1);
    bkt[ofs[d] + pos] = e;
}

// ---------------------------------------------------------------------------
// t[node] = sum_{e: dst=node} h[src(e)] * ew[e] — TWO nodes per block
// (half = tid>>7), uint4 gathers (125 lanes x 16 B = one 2 KB row / edge).
// Sum order per element identical to the 1-node version (bitwise-same agg).
// Threads 125..127 of each half zero k-pad cols 1000..1023.
// ---------------------------------------------------------------------------
__global__ __launch_bounds__(256) void node_agg(const int* __restrict__ ei,
                                                const float* __restrict__ ew,
                                                const int* __restrict__ ofs,
                                                const int* __restrict__ bkt,
                                                const u16* __restrict__ hsrc,
                                                u16* __restrict__ agg) {
    __shared__ int   s_src[2][32];
    __shared__ float s_w[2][32];
    __shared__ int   s_it[2];
    int tid = threadIdx.x;
    int half = tid >> 7, t = tid & 127;
    int node = blockIdx.x * 2 + half;        // grid 10000 -> nodes 0..19999
    int beg = ofs[node], end = ofs[node + 1];
    if (t == 0) s_it[half] = (end - beg + 31) >> 5;
    __syncthreads();
    int iters = max(s_it[0], s_it[1]);
    float acc[8] = {};
    for (int it = 0; it < iters; it++) {
        int cb = beg + it * 32;
        int n = min(32, end - cb);           // may be <= 0 for the short half
        if (t < n) {
            int e = bkt[cb + t];
            s_src[half][t] = ei[e];
            s_w[half][t]   = ew[e];
        }
        __syncthreads();
        if (t < 125) {
            for (int j = 0; j < n; j++) {
                int src = s_src[half][j];
                float w = s_w[half][j];
                uint4 v = *(const uint4*)(hsrc + (size_t)src * KP + t * 8);
                const u16* p = (const u16*)&v;
#pragma unroll
                for (int k = 0; k < 8; k++) acc[k] += b2f(p[k]) * w;
            }
        }
        __syncthreads();
    }
    if (t < 125) {
        u32 o[4] = {pack2(acc[0], acc[1]), pack2(acc[2], acc[3]),
                    pack2(acc[4], acc[5]), pack2(acc[6], acc[7])};
        *(uint4*)(agg + (size_t)node * KP + t * 8) = *(const uint4*)o;
    } else if (t < 128) {                    // zero pad cols 1000..1023
        uint4 z = {0, 0, 0, 0};
        *(uint4*)(agg + (size_t)node * KP + 1000 + (t - 125) * 8) = z;
    }
}

// ---------------------------------------------------------------------------
// Wc precompute: Wc_l[g, din] = sum_dout wihb[g][dout] * Wb3_l[din][dout]
// -> written into phase-1 half of wcat_l (slab = g/1000, row = g%1000).
// 128x128 tile, BK=64, XOR-swizzled staging. grid (192, 3).
// ---------------------------------------------------------------------------
__global__ __launch_bounds__(256) void gemm_wc(const u16* __restrict__ A,
                                               const u16* __restrict__ Bt3,
                                               u16* __restrict__ wcat) {
    __shared__ u16 S[16384];             // Sa [128][64] @0, Sb @8192 (u16 idx)
    int tid = threadIdx.x;
    int lane = tid & 63, wave = tid >> 6;
    int wr = wave >> 1, wc = wave & 1;
    int bid = blockIdx.x;
    int l = blockIdx.y;
    int m0 = (bid >> 3) * 128, n0 = (bid & 7) * 128;
    const u16* Bt = Bt3 + (size_t)l * 1048576;

    int aoff[4], boff[4];
#pragma unroll
    for (int i = 0; i < 4; i++) {
        int c = tid + 256 * i;
        int row = c >> 3, sl = c & 7;
        int kc = sl ^ (row & 7);
        aoff[i] = (m0 + row) * KP + kc * 8;
        boff[i] = (n0 + row) * KP + kc * 8;
    }
    f32x4 acc[4][4] = {};
    int fr = lane & 15, q = lane >> 4, sw = fr & 7;

    for (int k0 = 0; k0 < KP; k0 += 64) {
#pragma unroll
        for (int i = 0; i < 4; i++) {
            gl2lds16(A + aoff[i] + k0, &S[tid * 8 + 2048 * i]);
            gl2lds16(Bt + boff[i] + k0, &S[8192 + tid * 8 + 2048 * i]);
        }
        __syncthreads();
#pragma unroll
        for (int ks = 0; ks < 2; ks++) {
            int kx = ((ks * 4 + q) ^ sw) * 8;
            bf16x8 af[4], bf[4];
#pragma unroll
            for (int i = 0; i < 4; i++)
                af[i] = *(const bf16x8*)&S[(wr * 64 + i * 16 + fr) * 64 + kx];
#pragma unroll
            for (int j = 0; j < 4; j++)
                bf[j] = *(const bf16x8*)&S[8192 + (wc * 64 + j * 16 + fr) * 64 + kx];
#pragma unroll
            for (int i = 0; i < 4; i++)
#pragma unroll
                for (int j = 0; j < 4; j++)
                    acc[i][j] = mfma16(af[i], bf[j], acc[i][j]);
        }
        __syncthreads();
    }

    u16* wl = wcat + (size_t)l * WCAT_L;
    int cc = lane & 15, r4 = q * 4;
#pragma unroll
    for (int i = 0; i < 4; i++)
#pragma unroll
        for (int j = 0; j < 4; j++) {
            int gn = n0 + wc * 64 + j * 16 + cc;     // din column
            if (gn >= DDIM) continue;
#pragma unroll
            for (int r = 0; r < 4; r++) {
                int gm = m0 + wr * 64 + i * 16 + r4 + r;   // gate row 0..3071
                if (gm >= 3000) continue;
                int slab = (gm >= 2000) ? 2 : (gm >= 1000 ? 1 : 0);
                int row = gm - slab * 1000;
                wl[(size_t)slab * 2097152 + (size_t)row * 2048 + gn] =
                    f2b(acc[i][j][r]);
            }
        }
}

// ---------------------------------------------------------------------------
// Fused GRU, stacked-K, 2-blocks-per-CU drift schedule (R6):
//   R4/R5 identical counters refuted A-direct-to-reg (scattered loads are
//   TA/TCP throughput-bound: 16 cache lines per wave-instr, 4x the gl2lds
//   request count — slack-independent). Revert A to LDS staging (R2 path).
//   R2's residual: one 8-wave barrier-locked block per CU serializes the
//   per-tile LDS burst (1920 cyc) against the MFMA burst (1862 cyc).
//   Fix per m114 (separate waves on one CU overlap MFMA/VALU pipes fully):
//   TWO independent blocks per CU, drifting out of phase. BM=128, 4 waves
//   (256 thr), per-wave tile unchanged (64 rows x 32 cols, 48 MFMA/tile,
//   128 f32 acc). LDS = A dbuf 2x[128][64] (32 KB) + W dbuf 2x[3][64][64]
//   (48 KB) = 80 KB -> exactly 2 blocks / 160 KB CU.
//   Schedule = guide T3 minimum 2-phase: STAGE(t+1) at tile top (4 A + 6 W
//   gl2lds), compute tile t (8 af + 12 wf ds_read_b128, 48 MFMA),
//   __syncthreads (drain has a full tile of slack; cross-block drift covers
//   it). XOR swizzle as before (conflict-free, proven).
//   Grid 2512 = 8 xcd x 157 panels x 2 hi (hi INNER: panel pair shares A
//   via XCD L2 — keeps FETCH at ~366 MB).
//   Numerics bitwise-identical to R2 (same K order per accumulator).
// ---------------------------------------------------------------------------
__global__ __launch_bounds__(256, 2) void gru_fused(const u16* __restrict__ agg,
                                                    const u16* __restrict__ h,
                                                    const u16* __restrict__ wcat,
                                                    const float* __restrict__ bih,
                                                    const float* __restrict__ bhh,
                                                    u16* __restrict__ hout) {
    extern __shared__ u16 S[];   // A: 2x8192 @0/8192 ; W: 2x12288 @16384/28672
    int tid = threadIdx.x;
    int lane = tid & 63, wave = tid >> 6;      // 4 waves
    int wr = wave >> 1, wc = wave & 1;         // wave tile: 64 rows x 32 cols

    int bid = blockIdx.x;                 // grid 2512 = 8 xcd x (157 panels x 2 hi)
    int xcd = bid & 7;
    int s = bid >> 3;                     // 0..313
    int panel = s >> 1, hi = s & 1;
    int m0 = panel * 128;                 // rows >= 20000: finite garbage, masked
    int n0 = (xcd * 2 + hi) * 64;

    // staging maps (XOR swizzle): A slot c (row=c>>3, sl=c&7), kc=sl^(row&7)
    int aoff[4];
#pragma unroll
    for (int i = 0; i < 4; i++) {
        int c = tid + 256 * i;            // 0..1023: A rows 0..127
        int row = c >> 3, sl = c & 7;
        int kc = sl ^ (row & 7);
        aoff[i] = (m0 + row) * KP + kc * 8;
    }
    // W: 6 rounds of 256 chunks; c = tid+256*i, gate g=c>>9, within-gate
    // cg=c&511 -> row=cg>>3 (0..63), sl=cg&7; LDS dest linear = tid*8+i*2048
    int wsrc[6];
#pragma unroll
    for (int i = 0; i < 6; i++) {
        int c = tid + 256 * i;
        int g = c >> 9, cg = c & 511;
        int row = cg >> 3, sl = cg & 7;
        int kc = sl ^ (row & 7);
        wsrc[i] = g * 2097152 + (n0 + row) * 2048 + kc * 8;
    }

    f32x4 aR[4][2] = {}, aZ[4][2] = {}, aN[4][2] = {}, aH[4][2] = {};
    int fr = lane & 15, q = lane >> 4, sw = fr & 7;
    int kx0 = (q ^ sw) * 8, kx1 = ((4 + q) ^ sw) * 8;
    int arow[4], wcol[2];
#pragma unroll
    for (int i = 0; i < 4; i++) arow[i] = (wr * 64 + i * 16 + fr) * 64;
#pragma unroll
    for (int j = 0; j < 2; j++) wcol[j] = (wc * 32 + j * 16 + fr) * 64;

#define STAGE_AW(ts) do {                                                     \
        const u16* ap_ = ((ts) < 16) ? agg : h;                               \
        int kb_ = ((ts) < 16) ? (ts) * 64 : (ts) * 64 - 1024;                 \
        int ab_ = ((ts) & 1) * 8192, wb_ = 16384 + ((ts) & 1) * 12288;        \
        _Pragma("unroll")                                                     \
        for (int i_ = 0; i_ < 4; i_++)                                        \
            gl2lds16(ap_ + aoff[i_] + kb_, &S[ab_ + tid * 8 + 2048 * i_]);    \
        int kw_ = (ts) * 64;                                                  \
        _Pragma("unroll")                                                     \
        for (int i_ = 0; i_ < 6; i_++)                                        \
            gl2lds16(wcat + wsrc[i_] + kw_, &S[wb_ + tid * 8 + 2048 * i_]);   \
    } while (0)

// one gate: 4 ds_read_b128 + 16 MFMA; per-acc order = ks0, ks1 (as R2)
#define GATE(g_, ACC) do {                                                    \
        _Pragma("unroll")                                                     \
        for (int j_ = 0; j_ < 2; j_++) {                                      \
            bf16x8 w0_ = *(const bf16x8*)&S[Wb + (g_) * 4096 + wcol[j_] + kx0];\
            bf16x8 w1_ = *(const bf16x8*)&S[Wb + (g_) * 4096 + wcol[j_] + kx1];\
            _Pragma("unroll")                                                 \
            for (int i_ = 0; i_ < 4; i_++) {                                  \
                ACC[i_][j_] = mfma16(af[i_][0], w0_, ACC[i_][j_]);            \
                ACC[i_][j_] = mfma16(af[i_][1], w1_, ACC[i_][j_]);            \
            }                                                                 \
        }                                                                     \
    } while (0)

    // prologue: stage tile 0, drain, enter loop
    STAGE_AW(0);
    __syncthreads();

#pragma unroll 1
    for (int t = 0; t < 32; t++) {
        if (t <= 30) STAGE_AW(t + 1);     // issue next tile's 10 DMAs first
        int Ab = (t & 1) * 8192;
        int Wb = 16384 + (t & 1) * 12288;
        bf16x8 af[4][2];
#pragma unroll
        for (int i = 0; i < 4; i++) {     // A frags: read once, feed 3 gates
            af[i][0] = *(const bf16x8*)&S[Ab + arow[i] + kx0];
            af[i][1] = *(const bf16x8*)&S[Ab + arow[i] + kx1];
        }
        GATE(0, aR);
        GATE(1, aZ);
        if (t < 16) GATE(2, aN); else GATE(2, aH);
        if (t <= 30) __syncthreads();     // drain: full-tile slack; 2nd block
    }                                     // on the CU covers the stall
#undef STAGE_AW
#undef GATE

    // epilogue: gate math + h blend (same numerics as previous kernel)
    int cc = lane & 15, r4 = q * 4;
#pragma unroll
    for (int j = 0; j < 2; j++) {
        int gn = n0 + wc * 32 + j * 16 + cc;
        if (gn >= DDIM) continue;
        float br  = bih[gn] + bhh[gn];
        float bz  = bih[1000 + gn] + bhh[1000 + gn];
        float bni = bih[2000 + gn];
        float bnh = bhh[2000 + gn];
#pragma unroll
        for (int i = 0; i < 4; i++)
#pragma unroll
            for (int r = 0; r < 4; r++) {
                int gm = m0 + wr * 64 + i * 16 + r4 + r;
                if (gm >= N_NODES) continue;
                float rg = fsigmoid_(aR[i][j][r] + br);
                float zg = fsigmoid_(aZ[i][j][r] + bz);
                float ng = ftanh_(aN[i][j][r] + bni + rg * (aH[i][j][r] + bnh));
                size_t idx = (size_t)gm * KP + gn;
                float hp = b2f(h[idx]);
                hout[idx] = f2b((1.0f - zg) * ng + zg * hp);
            }
    }
}

// ---------------------------------------------------------------------------
// out[row] (fp32) = relu(h[row]) . fc_w + fc_b — one wave per row, uint4 loads
// ---------------------------------------------------------------------------
__global__ __launch_bounds__(256) void fc_out(const u16* __restrict__ h,
                                              const float* __restrict__ fw,
                                              const float* __restrict__ fb,
                                              float* __restrict__ out) {
    int row = blockIdx.x * 4 + (threadIdx.x >> 6);
    int lane = threadIdx.x & 63;
    if (row >= N_NODES) return;
    float s = 0.0f;
#pragma unroll
    for (int i = 0; i < 2; i++) {
        int c = lane + 64 * i;               // chunk of 8 elems
        if (c < 125) {
            uint4 v = *(const uint4*)(h + (size_t)row * KP + c * 8);
            const u16* pv = (const u16*)&v;
            float4 w0 = *(const float4*)(fw + c * 8);
            float4 w1 = *(const float4*)(fw + c * 8 + 4);
            const float* wp = (const float*)&w0;
            float hv;
#pragma unroll
            for (int k = 0; k < 4; k++) {
                hv = b2f(pv[k]);
                s += (hv > 0.0f ? hv : 0.0f) * wp[k];
            }
            wp = (const float*)&w1;
#pragma unroll
            for (int k = 0; k < 4; k++) {
                hv = b2f(pv[4 + k]);
                s += (hv > 0.0f ? hv : 0.0f) * wp[k];
            }
        }
    }
    for (int off = 32; off > 0; off >>= 1) s += __shfl_down(s, off, 64);
    if (lane == 0) out[row] = s + fb[0];
}

// ---------------------------------------------------------------------------
extern "C" void kernel_launch(void* const* d_in, const int* in_sizes, int n_in,
                              void* d_out, int out_size, void* d_ws, size_t ws_size,
                              hipStream_t stream) {
    const float* x   = (const float*)d_in[0];
    const int*   ei  = (const int*)d_in[1];
    const float* ew  = (const float*)d_in[2];
    const float* W   = (const float*)d_in[3];
    const float* wih = (const float*)d_in[4];
    const float* whh = (const float*)d_in[5];
    const float* bih = (const float*)d_in[6];
    const float* bhh = (const float*)d_in[7];
    const float* fw  = (const float*)d_in[8];
    const float* fb  = (const float*)d_in[9];
    float* out = (float*)d_out;

    // allow 80 KB dynamic LDS for gru_fused (idempotent, not a stream op)
    hipFuncSetAttribute((const void*)gru_fused,
                        hipFuncAttributeMaxDynamicSharedMemorySize, 81920);

    // workspace (~163 MB)
    char* ws = (char*)d_ws;
    u16* xb   = (u16*)(ws);                    // [20096][1024] bf16
    u16* bufA = (u16*)(ws + (size_t)SP);       // h rotation / setup scratch
    u16* bufB = (u16*)(ws + (size_t)2 * SP);   // t (aggregate)
    u16* wcat = (u16*)(ws + 123600000);        // 37.75 MB [3][3][1024][2048]
    int* cnt  = (int*)(ws + 161400000);        // 80 KB   (cur adjacent)
    int* cur  = (int*)(ws + 161480000);        // 80 KB
    int* ofs  = (int*)(ws + 161560000);        // 80 KB + 4
    int* bkt  = (int*)(ws + 161640192);        // 640 KB

    // setup scratch inside bufA (free until layer-0 gru output)
    u16* wihb = bufA;                          // [3072][1024] (rows>=3000 junk ok)
    u16* Wb3  = bufA + 3145728;                // [3][1024][1024] (rows>=1000 junk ok)

    // one-time conversions + Wc precompute + CSR build.
    // No wcat memset: k-pad cols of valid outputs always multiply a ZERO A-pad
    // (cvt_rows / node_agg write zero pads; 0xAA poison is finite bf16), and
    // garbage weight ROWS feed only gn>=1000 outputs which epilogues discard.
    cvt_rows<<<N_NODES, 256, 0, stream>>>(x, xb);
    cvt_weights<<<15000, 256, 0, stream>>>(wih, W, whh, wihb, Wb3, wcat);
    gemm_wc<<<dim3(192, 3), 256, 0, stream>>>(wihb, Wb3, wcat);
    hipMemsetAsync(cnt, 0, 160000, stream);    // cnt + cur (contiguous)
    count_edges<<<625, 256, 0, stream>>>(ei, cnt);
    scan_offsets<<<1, 1024, 0, stream>>>(cnt, ofs);
    fill_buckets<<<625, 256, 0, stream>>>(ei, ofs, cur, bkt);

    // layer 0: t = S*x -> bufB; h1 = GRU(t, xb, wcat0) -> bufA
    node_agg<<<10000, 256, 0, stream>>>(ei, ew, ofs, bkt, xb, bufB);
    gru_fused<<<2512, 256, 81920, stream>>>(bufB, xb, wcat, bih, bhh, bufA);

    // layer 1: t = S*h1 -> bufB; h2 = GRU(t, bufA, wcat1) -> xb
    node_agg<<<10000, 256, 0, stream>>>(ei, ew, ofs, bkt, bufA, bufB);
    gru_fused<<<2512, 256, 81920, stream>>>(bufB, bufA, wcat + WCAT_L, bih, bhh, xb);

    // layer 2: t = S*h2 -> bufB; h3 = GRU(t, xb, wcat2) -> bufA
    node_agg<<<10000, 256, 0, stream>>>(ei, ew, ofs, bkt, xb, bufB);
    gru_fused<<<2512, 256, 81920, stream>>>(bufB, xb, wcat + 2 * WCAT_L, bih, bhh, bufA);

    // out = relu(h3) @ fc_w^T + fc_b
    fc_out<<<5000, 256, 0, stream>>>(bufA, fw, fb, out);
}